// Round 1
// baseline (5192.113 us; speedup 1.0000x reference)
//
#include <hip/hip_runtime.h>

#define N_DST   50000
#define D       128
#define BM      64
#define BK      32
#define AS_STRIDE 68    // 64 + 4 pad
#define BS_STRIDE 132   // 128 + 4 pad

// ---------------- scatter: ssum[dst] += feat[src], deg[dst] += 1 ----------------
__global__ void scatter_kernel(const float* __restrict__ feat,
                               const int* __restrict__ src,
                               const int* __restrict__ dst,
                               float* __restrict__ ssum,
                               float* __restrict__ deg,
                               int n_edges) {
    int idx = blockIdx.x * blockDim.x + threadIdx.x;   // (edge, col4)
    int e = idx >> 5;
    if (e >= n_edges) return;
    int c4 = (idx & 31) * 4;
    int s = src[e];
    int d = dst[e];
    float4 v = *(const float4*)&feat[s * D + c4];
    float* base = &ssum[d * D + c4];
    atomicAdd(base + 0, v.x);
    atomicAdd(base + 1, v.y);
    atomicAdd(base + 2, v.z);
    atomicAdd(base + 3, v.w);
    if ((idx & 31) == 0) atomicAdd(&deg[d], 1.0f);
}

// ---------------- deg -> 1/max(deg,1) ----------------
__global__ void invdeg_kernel(float* __restrict__ deg, int n) {
    int i = blockIdx.x * blockDim.x + threadIdx.x;
    if (i < n) deg[i] = 1.0f / fmaxf(deg[i], 1.0f);
}

// ---------------- GEMM: full[map(i)] = feat[i] @ Wself^T + (ssum[i]*inv) @ Wneigh^T ----
__launch_bounds__(256)
__global__ void gemm_kernel(const float* __restrict__ feat,
                            const float* __restrict__ ssum,
                            const float* __restrict__ invdeg,
                            const float* __restrict__ Wself,
                            const float* __restrict__ Wneigh,
                            const int* __restrict__ reuse_idx,
                            float* __restrict__ full,
                            int n_reuse) {
    __shared__ float As[BK * AS_STRIDE];
    __shared__ float Bs[BK * BS_STRIDE];
    __shared__ int rowmap[BM];

    int tid = threadIdx.x;
    int tx = tid & 31;       // col group: cols tx*4 .. tx*4+3
    int ty = tid >> 5;       // row group: rows ty*8 .. ty*8+7
    int blockRow = blockIdx.x * BM;

    // per-row output position in `full`: j = i + r*, r* = first r with reuse[r]-r > i
    if (tid < BM) {
        int i = blockRow + tid;
        int j = -1;
        if (i < N_DST) {
            int lo = 0, hi = n_reuse;
            while (lo < hi) {
                int mid = (lo + hi) >> 1;
                if (reuse_idx[mid] - mid > i) hi = mid; else lo = mid + 1;
            }
            j = i + lo;
        }
        rowmap[tid] = j;
    }

    float acc[8][4];
#pragma unroll
    for (int i = 0; i < 8; ++i)
#pragma unroll
        for (int c = 0; c < 4; ++c) acc[i][c] = 0.0f;

    // A loader: 64 rows x 32 k, 4 threads/row, 2 float4 each
    int aRow  = tid >> 2;
    int aCol0 = (tid & 3) * 8;
    int gRow  = blockRow + aRow;
    bool aValid = gRow < N_DST;
    // B loader: 128 cols x 32 k, 2 threads/col, 4 float4 each
    int bC  = tid >> 1;
    int bK0 = (tid & 1) * 16;

#pragma unroll
    for (int step = 0; step < 8; ++step) {
        int k0 = step * BK;
        bool isNeigh = (k0 >= 128);
        const float* Wsrc = isNeigh ? Wneigh : Wself;
        int kbase = isNeigh ? (k0 - 128) : k0;

        float4 av[2];
        if (aValid) {
            const float* Asrc = isNeigh ? ssum : feat;
            float sc = isNeigh ? invdeg[gRow] : 1.0f;
#pragma unroll
            for (int j = 0; j < 2; ++j) {
                float4 v = *(const float4*)&Asrc[gRow * D + kbase + aCol0 + j * 4];
                av[j] = make_float4(v.x * sc, v.y * sc, v.z * sc, v.w * sc);
            }
        } else {
            av[0] = av[1] = make_float4(0.f, 0.f, 0.f, 0.f);
        }
        float4 bv[4];
#pragma unroll
        for (int j = 0; j < 4; ++j)
            bv[j] = *(const float4*)&Wsrc[bC * D + kbase + bK0 + j * 4];

        __syncthreads();   // previous iteration's LDS reads done
        {
            float a0[8] = {av[0].x, av[0].y, av[0].z, av[0].w,
                           av[1].x, av[1].y, av[1].z, av[1].w};
#pragma unroll
            for (int q = 0; q < 8; ++q)
                As[(aCol0 + q) * AS_STRIDE + aRow] = a0[q];
            float b0[16] = {bv[0].x, bv[0].y, bv[0].z, bv[0].w,
                            bv[1].x, bv[1].y, bv[1].z, bv[1].w,
                            bv[2].x, bv[2].y, bv[2].z, bv[2].w,
                            bv[3].x, bv[3].y, bv[3].z, bv[3].w};
#pragma unroll
            for (int q = 0; q < 16; ++q)
                Bs[(bK0 + q) * BS_STRIDE + bC] = b0[q];
        }
        __syncthreads();

#pragma unroll
        for (int kk = 0; kk < BK; ++kk) {
            float4 b  = *(const float4*)&Bs[kk * BS_STRIDE + tx * 4];
            float4 a0 = *(const float4*)&As[kk * AS_STRIDE + ty * 8];
            float4 a1 = *(const float4*)&As[kk * AS_STRIDE + ty * 8 + 4];
            float a[8] = {a0.x, a0.y, a0.z, a0.w, a1.x, a1.y, a1.z, a1.w};
            float bb[4] = {b.x, b.y, b.z, b.w};
#pragma unroll
            for (int i = 0; i < 8; ++i)
#pragma unroll
                for (int c = 0; c < 4; ++c)
                    acc[i][c] += a[i] * bb[c];
        }
    }

    // epilogue: scatter rows to their position in `full`
#pragma unroll
    for (int i = 0; i < 8; ++i) {
        int j = rowmap[ty * 8 + i];
        if (j >= 0) {
            *(float4*)&full[j * D + tx * 4] =
                make_float4(acc[i][0], acc[i][1], acc[i][2], acc[i][3]);
        }
    }
}

// ---------------- reuse rows: full[reuse_idx[r]] = emb[r] ----------------
__global__ void reuse_copy_kernel(const float* __restrict__ emb,
                                  const int* __restrict__ ridx,
                                  float* __restrict__ full, int n) {
    int idx = blockIdx.x * blockDim.x + threadIdx.x;
    int r = idx >> 5;
    if (r >= n) return;
    int c4 = (idx & 31) * 4;
    *(float4*)&full[ridx[r] * D + c4] = *(const float4*)&emb[r * D + c4];
}

// ---------------- cache gather: out[t] = full[cidx[t]] ----------------
__global__ void cache_gather_kernel(const float* __restrict__ full,
                                    const int* __restrict__ cidx,
                                    float* __restrict__ out, int n) {
    int idx = blockIdx.x * blockDim.x + threadIdx.x;
    int r = idx >> 5;
    if (r >= n) return;
    int c4 = (idx & 31) * 4;
    *(float4*)&out[r * D + c4] = *(const float4*)&full[cidx[r] * D + c4];
}

extern "C" void kernel_launch(void* const* d_in, const int* in_sizes, int n_in,
                              void* d_out, int out_size, void* d_ws, size_t ws_size,
                              hipStream_t stream) {
    const float* feat_src  = (const float*)d_in[0];
    const float* W_self    = (const float*)d_in[1];
    const float* W_neigh   = (const float*)d_in[2];
    const float* reuse_emb = (const float*)d_in[3];
    const int*   src       = (const int*)d_in[4];
    const int*   dst       = (const int*)d_in[5];
    const int*   reuse_idx = (const int*)d_in[6];
    const int*   cache_idx = (const int*)d_in[7];

    int n_edges = in_sizes[4];
    int n_reuse = in_sizes[6];
    int n_cache = in_sizes[7];
    int full_len = N_DST + n_reuse;

    float* ssum = (float*)d_ws;                       // 50000*128 floats
    float* deg  = ssum + (size_t)N_DST * D;           // 50000 floats
    float* full = (float*)d_out;                      // 55000*128
    float* cache_out = full + (size_t)full_len * D;   // 8000*128

    size_t zero_bytes = (size_t)N_DST * D * sizeof(float) + (size_t)N_DST * sizeof(float);
    hipMemsetAsync(d_ws, 0, zero_bytes, stream);

    {
        int threads = n_edges * 32;
        scatter_kernel<<<(threads + 255) / 256, 256, 0, stream>>>(
            feat_src, src, dst, ssum, deg, n_edges);
    }
    invdeg_kernel<<<(N_DST + 255) / 256, 256, 0, stream>>>(deg, N_DST);

    gemm_kernel<<<(N_DST + BM - 1) / BM, 256, 0, stream>>>(
        feat_src, ssum, deg, W_self, W_neigh, reuse_idx, full, n_reuse);

    reuse_copy_kernel<<<(n_reuse * 32 + 255) / 256, 256, 0, stream>>>(
        reuse_emb, reuse_idx, full, n_reuse);

    cache_gather_kernel<<<(n_cache * 32 + 255) / 256, 256, 0, stream>>>(
        full, cache_idx, cache_out, n_cache);
}

// Round 2
// 1206.040 us; speedup vs baseline: 4.3051x; 4.3051x over previous
//
#include <hip/hip_runtime.h>

#define N_DST   50000
#define D       128
#define BM      64
#define BK      32
#define AS_STRIDE 68    // 64 + 4 pad (16B-aligned rows)
#define BS_STRIDE 132   // 128 + 4 pad

// ---------------- scatter: ssum[dst] += feat[src], deg[dst] += 1 ----------------
__global__ void scatter_kernel(const float* __restrict__ feat,
                               const int* __restrict__ src,
                               const int* __restrict__ dst,
                               float* __restrict__ ssum,
                               float* __restrict__ deg,
                               int n_edges) {
    int idx = blockIdx.x * blockDim.x + threadIdx.x;   // (edge, col4)
    int e = idx >> 5;
    if (e >= n_edges) return;
    int c4 = (idx & 31) * 4;
    int s = src[e];
    int d = dst[e];
    float4 v = *(const float4*)&feat[s * D + c4];
    float* base = &ssum[d * D + c4];
    atomicAdd(base + 0, v.x);
    atomicAdd(base + 1, v.y);
    atomicAdd(base + 2, v.z);
    atomicAdd(base + 3, v.w);
    if ((idx & 31) == 0) atomicAdd(&deg[d], 1.0f);
}

// ---------------- ssum[r] *= 1/max(deg[r],1)  (h_neigh in place) ----------------
__global__ void normalize_kernel(float* __restrict__ ssum,
                                 const float* __restrict__ deg) {
    int idx = blockIdx.x * blockDim.x + threadIdx.x;
    int r = idx >> 5;
    if (r >= N_DST) return;
    int c4 = (idx & 31) * 4;
    float sc = 1.0f / fmaxf(deg[r], 1.0f);
    float4 v = *(const float4*)&ssum[r * D + c4];
    v.x *= sc; v.y *= sc; v.z *= sc; v.w *= sc;
    *(float4*)&ssum[r * D + c4] = v;
}

// ---- GEMM: full[map(i)] = feat[i] @ Wself^T + hneigh[i] @ Wneigh^T ----
// Register-pressure disciplined: outer step loop NOT unrolled, 128-VGPR cap.
__global__ __launch_bounds__(256, 4)
void gemm_kernel(const float* __restrict__ feat,
                 const float* __restrict__ hneigh,
                 const float* __restrict__ Wself,
                 const float* __restrict__ Wneigh,
                 const int* __restrict__ reuse_idx,
                 float* __restrict__ full,
                 int n_reuse) {
    __shared__ float As[BK * AS_STRIDE];   // [k][row] transposed
    __shared__ float Bs[BK * BS_STRIDE];   // [k][col] transposed
    __shared__ int rowmap[BM];

    int tid = threadIdx.x;
    int tx = tid & 31;       // cols tx*4 .. tx*4+3
    int ty = tid >> 5;       // rows ty*8 .. ty*8+7
    int blockRow = blockIdx.x * BM;

    // output row position in `full`: j = i + r*, r* = first r with reuse[r]-r > i
    if (tid < BM) {
        int i = blockRow + tid;
        int j = -1;
        if (i < N_DST) {
            int lo = 0, hi = n_reuse;
            while (lo < hi) {
                int mid = (lo + hi) >> 1;
                if (reuse_idx[mid] - mid > i) hi = mid; else lo = mid + 1;
            }
            j = i + lo;
        }
        rowmap[tid] = j;
    }

    float acc[8][4];
#pragma unroll
    for (int i = 0; i < 8; ++i)
#pragma unroll
        for (int c = 0; c < 4; ++c) acc[i][c] = 0.0f;

    // A loader: 64 rows x 32 k; thread (aRow, at) loads k = {4*at..4*at+3, 16+4*at..+3}
    int aRow = tid >> 2;
    int at   = tid & 3;
    int gRow = blockRow + aRow;
    bool aValid = gRow < N_DST;
    // B loader: 128 cols x 32 k; thread (bC, half) loads 16 consecutive k
    int bC  = tid >> 1;
    int bK0 = (tid & 1) * 16;

#pragma unroll 1
    for (int step = 0; step < 8; ++step) {
        const float* Asrc = (step < 4) ? feat : hneigh;
        const float* Wsrc = (step < 4) ? Wself : Wneigh;
        int kbase = (step & 3) * BK;

        float4 av0 = make_float4(0.f, 0.f, 0.f, 0.f);
        float4 av1 = av0;
        if (aValid) {
            av0 = *(const float4*)&Asrc[gRow * D + kbase + 4 * at];
            av1 = *(const float4*)&Asrc[gRow * D + kbase + 16 + 4 * at];
        }
        float4 bv0 = *(const float4*)&Wsrc[bC * D + kbase + bK0];
        float4 bv1 = *(const float4*)&Wsrc[bC * D + kbase + bK0 + 4];
        float4 bv2 = *(const float4*)&Wsrc[bC * D + kbase + bK0 + 8];
        float4 bv3 = *(const float4*)&Wsrc[bC * D + kbase + bK0 + 12];

        __syncthreads();   // previous iteration's LDS reads done
        // As writes: addr%32 = (16*at + 4q + aRow)%32 -> 2-way aliasing (free)
        As[(4 * at + 0) * AS_STRIDE + aRow] = av0.x;
        As[(4 * at + 1) * AS_STRIDE + aRow] = av0.y;
        As[(4 * at + 2) * AS_STRIDE + aRow] = av0.z;
        As[(4 * at + 3) * AS_STRIDE + aRow] = av0.w;
        As[(16 + 4 * at + 0) * AS_STRIDE + aRow] = av1.x;
        As[(16 + 4 * at + 1) * AS_STRIDE + aRow] = av1.y;
        As[(16 + 4 * at + 2) * AS_STRIDE + aRow] = av1.z;
        As[(16 + 4 * at + 3) * AS_STRIDE + aRow] = av1.w;
        Bs[(bK0 + 0)  * BS_STRIDE + bC] = bv0.x;
        Bs[(bK0 + 1)  * BS_STRIDE + bC] = bv0.y;
        Bs[(bK0 + 2)  * BS_STRIDE + bC] = bv0.z;
        Bs[(bK0 + 3)  * BS_STRIDE + bC] = bv0.w;
        Bs[(bK0 + 4)  * BS_STRIDE + bC] = bv1.x;
        Bs[(bK0 + 5)  * BS_STRIDE + bC] = bv1.y;
        Bs[(bK0 + 6)  * BS_STRIDE + bC] = bv1.z;
        Bs[(bK0 + 7)  * BS_STRIDE + bC] = bv1.w;
        Bs[(bK0 + 8)  * BS_STRIDE + bC] = bv2.x;
        Bs[(bK0 + 9)  * BS_STRIDE + bC] = bv2.y;
        Bs[(bK0 + 10) * BS_STRIDE + bC] = bv2.z;
        Bs[(bK0 + 11) * BS_STRIDE + bC] = bv2.w;
        Bs[(bK0 + 12) * BS_STRIDE + bC] = bv3.x;
        Bs[(bK0 + 13) * BS_STRIDE + bC] = bv3.y;
        Bs[(bK0 + 14) * BS_STRIDE + bC] = bv3.z;
        Bs[(bK0 + 15) * BS_STRIDE + bC] = bv3.w;
        __syncthreads();

#pragma unroll
        for (int kk = 0; kk < BK; ++kk) {
            float4 b  = *(const float4*)&Bs[kk * BS_STRIDE + tx * 4];
            float4 a0 = *(const float4*)&As[kk * AS_STRIDE + ty * 8];
            float4 a1 = *(const float4*)&As[kk * AS_STRIDE + ty * 8 + 4];
#define FMA_ROW(i, aval) \
            acc[i][0] += (aval) * b.x; acc[i][1] += (aval) * b.y; \
            acc[i][2] += (aval) * b.z; acc[i][3] += (aval) * b.w;
            FMA_ROW(0, a0.x) FMA_ROW(1, a0.y) FMA_ROW(2, a0.z) FMA_ROW(3, a0.w)
            FMA_ROW(4, a1.x) FMA_ROW(5, a1.y) FMA_ROW(6, a1.z) FMA_ROW(7, a1.w)
#undef FMA_ROW
        }
    }

    // epilogue: scatter rows to their position in `full`
#pragma unroll
    for (int i = 0; i < 8; ++i) {
        int j = rowmap[ty * 8 + i];
        if (j >= 0) {
            *(float4*)&full[j * D + tx * 4] =
                make_float4(acc[i][0], acc[i][1], acc[i][2], acc[i][3]);
        }
    }
}

// ---------------- reuse rows: full[reuse_idx[r]] = emb[r] ----------------
__global__ void reuse_copy_kernel(const float* __restrict__ emb,
                                  const int* __restrict__ ridx,
                                  float* __restrict__ full, int n) {
    int idx = blockIdx.x * blockDim.x + threadIdx.x;
    int r = idx >> 5;
    if (r >= n) return;
    int c4 = (idx & 31) * 4;
    *(float4*)&full[ridx[r] * D + c4] = *(const float4*)&emb[r * D + c4];
}

// ---------------- cache gather: out[t] = full[cidx[t]] ----------------
__global__ void cache_gather_kernel(const float* __restrict__ full,
                                    const int* __restrict__ cidx,
                                    float* __restrict__ out, int n) {
    int idx = blockIdx.x * blockDim.x + threadIdx.x;
    int r = idx >> 5;
    if (r >= n) return;
    int c4 = (idx & 31) * 4;
    *(float4*)&out[r * D + c4] = *(const float4*)&full[cidx[r] * D + c4];
}

extern "C" void kernel_launch(void* const* d_in, const int* in_sizes, int n_in,
                              void* d_out, int out_size, void* d_ws, size_t ws_size,
                              hipStream_t stream) {
    const float* feat_src  = (const float*)d_in[0];
    const float* W_self    = (const float*)d_in[1];
    const float* W_neigh   = (const float*)d_in[2];
    const float* reuse_emb = (const float*)d_in[3];
    const int*   src       = (const int*)d_in[4];
    const int*   dst       = (const int*)d_in[5];
    const int*   reuse_idx = (const int*)d_in[6];
    const int*   cache_idx = (const int*)d_in[7];

    int n_edges = in_sizes[4];
    int n_reuse = in_sizes[6];
    int n_cache = in_sizes[7];
    int full_len = N_DST + n_reuse;

    float* ssum = (float*)d_ws;                       // 50000*128 floats
    float* deg  = ssum + (size_t)N_DST * D;           // 50000 floats
    float* full = (float*)d_out;                      // 55000*128
    float* cache_out = full + (size_t)full_len * D;   // 8000*128

    size_t zero_bytes = (size_t)N_DST * D * sizeof(float) + (size_t)N_DST * sizeof(float);
    hipMemsetAsync(d_ws, 0, zero_bytes, stream);

    {
        int threads = n_edges * 32;
        scatter_kernel<<<(threads + 255) / 256, 256, 0, stream>>>(
            feat_src, src, dst, ssum, deg, n_edges);
    }
    normalize_kernel<<<(N_DST * 32 + 255) / 256, 256, 0, stream>>>(ssum, deg);

    gemm_kernel<<<(N_DST + BM - 1) / BM, 256, 0, stream>>>(
        feat_src, ssum, W_self, W_neigh, reuse_idx, full, n_reuse);

    reuse_copy_kernel<<<(n_reuse * 32 + 255) / 256, 256, 0, stream>>>(
        reuse_emb, reuse_idx, full, n_reuse);

    cache_gather_kernel<<<(n_cache * 32 + 255) / 256, 256, 0, stream>>>(
        full, cache_idx, cache_out, n_cache);
}

// Round 3
// 235.188 us; speedup vs baseline: 22.0765x; 5.1280x over previous
//
#include <hip/hip_runtime.h>

#define N_DST   50000
#define D       128
#define MAXDEG  128     // Poisson(12) row degree; P(deg>128) ~ 1e-90 for this data
#define BM      64
#define BK      32
#define AS_STRIDE 68    // 64 + 4 pad (16B-aligned rows)
#define BS_STRIDE 132   // 128 + 4 pad

// ---------------- build ELL adjacency: int atomics only ----------------
__global__ void build_ell_kernel(const int* __restrict__ src,
                                 const int* __restrict__ dst,
                                 int* __restrict__ ell,
                                 int* __restrict__ cnt,
                                 int n_edges) {
    int e = blockIdx.x * blockDim.x + threadIdx.x;
    if (e >= n_edges) return;
    int d = dst[e];
    int pos = atomicAdd(&cnt[d], 1);
    if (pos < MAXDEG)   // overflow impossible for this distribution; guard anyway
        ell[(size_t)d * MAXDEG + pos] = src[e];
}

// ---------------- pull-gather: hneigh[r] = (1/max(deg,1)) * sum feat[ell[r][*]] ----
// One wave per dst row; lane covers cols {2*lane, 2*lane+1} (512 B coalesced/row).
__global__ __launch_bounds__(256)
void gather_kernel(const float* __restrict__ feat,
                   const int* __restrict__ ell,
                   const int* __restrict__ cnt,
                   float* __restrict__ hneigh) {
    int gid  = blockIdx.x * blockDim.x + threadIdx.x;
    int row  = gid >> 6;
    int lane = threadIdx.x & 63;
    if (row >= N_DST) return;

    int deg = cnt[row];
    int n = min(deg, MAXDEG);
    float inv = 1.0f / fmaxf((float)deg, 1.0f);
    const int* rell = ell + (size_t)row * MAXDEG;

    float2 acc = make_float2(0.f, 0.f);
    int j = 0;
    for (; j + 4 <= n; j += 4) {
        int s0 = rell[j + 0];
        int s1 = rell[j + 1];
        int s2 = rell[j + 2];
        int s3 = rell[j + 3];
        float2 v0 = *(const float2*)&feat[(size_t)s0 * D + 2 * lane];
        float2 v1 = *(const float2*)&feat[(size_t)s1 * D + 2 * lane];
        float2 v2 = *(const float2*)&feat[(size_t)s2 * D + 2 * lane];
        float2 v3 = *(const float2*)&feat[(size_t)s3 * D + 2 * lane];
        acc.x += v0.x + v1.x + v2.x + v3.x;
        acc.y += v0.y + v1.y + v2.y + v3.y;
    }
    for (; j < n; ++j) {
        int s = rell[j];
        float2 v = *(const float2*)&feat[(size_t)s * D + 2 * lane];
        acc.x += v.x;
        acc.y += v.y;
    }
    *(float2*)&hneigh[(size_t)row * D + 2 * lane] =
        make_float2(acc.x * inv, acc.y * inv);
}

// ---- GEMM: full[map(i)] = feat[i] @ Wself^T + hneigh[i] @ Wneigh^T ----
__global__ __launch_bounds__(256, 4)
void gemm_kernel(const float* __restrict__ feat,
                 const float* __restrict__ hneigh,
                 const float* __restrict__ Wself,
                 const float* __restrict__ Wneigh,
                 const int* __restrict__ reuse_idx,
                 float* __restrict__ full,
                 int n_reuse) {
    __shared__ float As[BK * AS_STRIDE];   // [k][row] transposed
    __shared__ float Bs[BK * BS_STRIDE];   // [k][col] transposed
    __shared__ int rowmap[BM];

    int tid = threadIdx.x;
    int tx = tid & 31;       // cols tx*4 .. tx*4+3
    int ty = tid >> 5;       // rows ty*8 .. ty*8+7
    int blockRow = blockIdx.x * BM;

    // output row position in `full`: j = i + r*, r* = first r with reuse[r]-r > i
    if (tid < BM) {
        int i = blockRow + tid;
        int j = -1;
        if (i < N_DST) {
            int lo = 0, hi = n_reuse;
            while (lo < hi) {
                int mid = (lo + hi) >> 1;
                if (reuse_idx[mid] - mid > i) hi = mid; else lo = mid + 1;
            }
            j = i + lo;
        }
        rowmap[tid] = j;
    }

    float acc[8][4];
#pragma unroll
    for (int i = 0; i < 8; ++i)
#pragma unroll
        for (int c = 0; c < 4; ++c) acc[i][c] = 0.0f;

    // A loader: 64 rows x 32 k; thread (aRow, at) loads k = {4*at..+3, 16+4*at..+3}
    int aRow = tid >> 2;
    int at   = tid & 3;
    int gRow = blockRow + aRow;
    bool aValid = gRow < N_DST;
    // B loader: 128 cols x 32 k; thread (bC, half) loads 16 consecutive k
    int bC  = tid >> 1;
    int bK0 = (tid & 1) * 16;

#pragma unroll 1
    for (int step = 0; step < 8; ++step) {
        const float* Asrc = (step < 4) ? feat : hneigh;
        const float* Wsrc = (step < 4) ? Wself : Wneigh;
        int kbase = (step & 3) * BK;

        float4 av0 = make_float4(0.f, 0.f, 0.f, 0.f);
        float4 av1 = av0;
        if (aValid) {
            av0 = *(const float4*)&Asrc[gRow * D + kbase + 4 * at];
            av1 = *(const float4*)&Asrc[gRow * D + kbase + 16 + 4 * at];
        }
        float4 bv0 = *(const float4*)&Wsrc[bC * D + kbase + bK0];
        float4 bv1 = *(const float4*)&Wsrc[bC * D + kbase + bK0 + 4];
        float4 bv2 = *(const float4*)&Wsrc[bC * D + kbase + bK0 + 8];
        float4 bv3 = *(const float4*)&Wsrc[bC * D + kbase + bK0 + 12];

        __syncthreads();   // previous iteration's LDS reads done
        As[(4 * at + 0) * AS_STRIDE + aRow] = av0.x;
        As[(4 * at + 1) * AS_STRIDE + aRow] = av0.y;
        As[(4 * at + 2) * AS_STRIDE + aRow] = av0.z;
        As[(4 * at + 3) * AS_STRIDE + aRow] = av0.w;
        As[(16 + 4 * at + 0) * AS_STRIDE + aRow] = av1.x;
        As[(16 + 4 * at + 1) * AS_STRIDE + aRow] = av1.y;
        As[(16 + 4 * at + 2) * AS_STRIDE + aRow] = av1.z;
        As[(16 + 4 * at + 3) * AS_STRIDE + aRow] = av1.w;
        Bs[(bK0 + 0)  * BS_STRIDE + bC] = bv0.x;
        Bs[(bK0 + 1)  * BS_STRIDE + bC] = bv0.y;
        Bs[(bK0 + 2)  * BS_STRIDE + bC] = bv0.z;
        Bs[(bK0 + 3)  * BS_STRIDE + bC] = bv0.w;
        Bs[(bK0 + 4)  * BS_STRIDE + bC] = bv1.x;
        Bs[(bK0 + 5)  * BS_STRIDE + bC] = bv1.y;
        Bs[(bK0 + 6)  * BS_STRIDE + bC] = bv1.z;
        Bs[(bK0 + 7)  * BS_STRIDE + bC] = bv1.w;
        Bs[(bK0 + 8)  * BS_STRIDE + bC] = bv2.x;
        Bs[(bK0 + 9)  * BS_STRIDE + bC] = bv2.y;
        Bs[(bK0 + 10) * BS_STRIDE + bC] = bv2.z;
        Bs[(bK0 + 11) * BS_STRIDE + bC] = bv2.w;
        Bs[(bK0 + 12) * BS_STRIDE + bC] = bv3.x;
        Bs[(bK0 + 13) * BS_STRIDE + bC] = bv3.y;
        Bs[(bK0 + 14) * BS_STRIDE + bC] = bv3.z;
        Bs[(bK0 + 15) * BS_STRIDE + bC] = bv3.w;
        __syncthreads();

#pragma unroll
        for (int kk = 0; kk < BK; ++kk) {
            float4 b  = *(const float4*)&Bs[kk * BS_STRIDE + tx * 4];
            float4 a0 = *(const float4*)&As[kk * AS_STRIDE + ty * 8];
            float4 a1 = *(const float4*)&As[kk * AS_STRIDE + ty * 8 + 4];
#define FMA_ROW(i, aval) \
            acc[i][0] += (aval) * b.x; acc[i][1] += (aval) * b.y; \
            acc[i][2] += (aval) * b.z; acc[i][3] += (aval) * b.w;
            FMA_ROW(0, a0.x) FMA_ROW(1, a0.y) FMA_ROW(2, a0.z) FMA_ROW(3, a0.w)
            FMA_ROW(4, a1.x) FMA_ROW(5, a1.y) FMA_ROW(6, a1.z) FMA_ROW(7, a1.w)
#undef FMA_ROW
        }
    }

#pragma unroll
    for (int i = 0; i < 8; ++i) {
        int j = rowmap[ty * 8 + i];
        if (j >= 0) {
            *(float4*)&full[j * D + tx * 4] =
                make_float4(acc[i][0], acc[i][1], acc[i][2], acc[i][3]);
        }
    }
}

// ---------------- reuse rows: full[reuse_idx[r]] = emb[r] ----------------
__global__ void reuse_copy_kernel(const float* __restrict__ emb,
                                  const int* __restrict__ ridx,
                                  float* __restrict__ full, int n) {
    int idx = blockIdx.x * blockDim.x + threadIdx.x;
    int r = idx >> 5;
    if (r >= n) return;
    int c4 = (idx & 31) * 4;
    *(float4*)&full[ridx[r] * D + c4] = *(const float4*)&emb[r * D + c4];
}

// ---------------- cache gather: out[t] = full[cidx[t]] ----------------
__global__ void cache_gather_kernel(const float* __restrict__ full,
                                    const int* __restrict__ cidx,
                                    float* __restrict__ out, int n) {
    int idx = blockIdx.x * blockDim.x + threadIdx.x;
    int r = idx >> 5;
    if (r >= n) return;
    int c4 = (idx & 31) * 4;
    *(float4*)&out[r * D + c4] = *(const float4*)&full[cidx[r] * D + c4];
}

extern "C" void kernel_launch(void* const* d_in, const int* in_sizes, int n_in,
                              void* d_out, int out_size, void* d_ws, size_t ws_size,
                              hipStream_t stream) {
    const float* feat_src  = (const float*)d_in[0];
    const float* W_self    = (const float*)d_in[1];
    const float* W_neigh   = (const float*)d_in[2];
    const float* reuse_emb = (const float*)d_in[3];
    const int*   src       = (const int*)d_in[4];
    const int*   dst       = (const int*)d_in[5];
    const int*   reuse_idx = (const int*)d_in[6];
    const int*   cache_idx = (const int*)d_in[7];

    int n_edges = in_sizes[4];
    int n_reuse = in_sizes[6];
    int n_cache = in_sizes[7];
    int full_len = N_DST + n_reuse;

    // ws layout: hneigh (50000*128 f32 = 25.6 MB) | cnt (50000 i32 = 0.2 MB)
    float* hneigh = (float*)d_ws;
    int*   cnt    = (int*)(hneigh + (size_t)N_DST * D);

    float* full = (float*)d_out;                      // 55000*128
    float* cache_out = full + (size_t)full_len * D;   // 8000*128

    // ELL adjacency (50000*128 i32 = 25.6 MB) lives temporarily in d_out's
    // `full` region (28.2 MB) — it is consumed by gather_kernel before the
    // GEMM overwrites the region, and every byte of d_out is written later.
    int* ell = (int*)full;

    hipMemsetAsync(cnt, 0, (size_t)N_DST * sizeof(int), stream);

    build_ell_kernel<<<(n_edges + 255) / 256, 256, 0, stream>>>(
        src, dst, ell, cnt, n_edges);

    gather_kernel<<<(N_DST * 64 + 255) / 256, 256, 0, stream>>>(
        feat_src, ell, cnt, hneigh);

    gemm_kernel<<<(N_DST + BM - 1) / BM, 256, 0, stream>>>(
        feat_src, hneigh, W_self, W_neigh, reuse_idx, full, n_reuse);

    reuse_copy_kernel<<<(n_reuse * 32 + 255) / 256, 256, 0, stream>>>(
        reuse_emb, reuse_idx, full, n_reuse);

    cache_gather_kernel<<<(n_cache * 32 + 255) / 256, 256, 0, stream>>>(
        full, cache_idx, cache_out, n_cache);
}

// Round 4
// 204.911 us; speedup vs baseline: 25.3384x; 1.1478x over previous
//
#include <hip/hip_runtime.h>

#define N_DST   50000
#define D       128
#define MAXDEG  128     // Poisson(12) row degree; P(deg>128) ~ 1e-90 for this data

typedef __attribute__((ext_vector_type(8))) short bf16x8;
typedef __attribute__((ext_vector_type(4))) float f32x4;

__device__ __forceinline__ unsigned short f2bf(float f) {
    unsigned u = __float_as_uint(f);
    u += 0x7FFFu + ((u >> 16) & 1u);   // RNE
    return (unsigned short)(u >> 16);
}

// ---------------- build ELL adjacency: int atomics only ----------------
__global__ void build_ell_kernel(const int* __restrict__ src,
                                 const int* __restrict__ dst,
                                 int* __restrict__ ell,
                                 int* __restrict__ cnt,
                                 int n_edges) {
    int e = blockIdx.x * blockDim.x + threadIdx.x;
    if (e >= n_edges) return;
    int d = dst[e];
    int pos = atomicAdd(&cnt[d], 1);
    if (pos < MAXDEG)
        ell[(size_t)d * MAXDEG + pos] = src[e];
}

// ---------------- rowpos[i] = position of GEMM row i in `full` ----------------
__global__ void rowpos_kernel(const int* __restrict__ reuse_idx,
                              int* __restrict__ rowpos, int n_reuse) {
    int i = blockIdx.x * blockDim.x + threadIdx.x;
    if (i >= N_DST) return;
    int lo = 0, hi = n_reuse;
    while (lo < hi) {
        int mid = (lo + hi) >> 1;
        if (reuse_idx[mid] - mid > i) hi = mid; else lo = mid + 1;
    }
    rowpos[i] = i + lo;
}

// ---------------- W -> bf16, combined [n][k0..255] = [Wself | Wneigh] ----------
__global__ void wconv_kernel(const float* __restrict__ Wself,
                             const float* __restrict__ Wneigh,
                             unsigned short* __restrict__ wbf) {
    int idx = blockIdx.x * blockDim.x + threadIdx.x;
    if (idx >= 128 * 256) return;
    int n = idx >> 8;
    int k = idx & 255;
    float v = (k < 128) ? Wself[n * 128 + k] : Wneigh[n * 128 + (k - 128)];
    wbf[idx] = f2bf(v);
}

// ---------------- pull-gather -> bf16 hneigh ----------------
__global__ __launch_bounds__(256)
void gather_kernel(const float* __restrict__ feat,
                   const int* __restrict__ ell,
                   const int* __restrict__ cnt,
                   unsigned int* __restrict__ hneigh_u32) {   // bf16x2 packed
    int gid  = blockIdx.x * blockDim.x + threadIdx.x;
    int row  = gid >> 6;
    int lane = threadIdx.x & 63;
    if (row >= N_DST) return;

    int deg = cnt[row];
    int n = min(deg, MAXDEG);
    float inv = 1.0f / fmaxf((float)deg, 1.0f);
    const int* rell = ell + (size_t)row * MAXDEG;

    float2 acc = make_float2(0.f, 0.f);
    int j = 0;
    for (; j + 4 <= n; j += 4) {
        int s0 = rell[j + 0];
        int s1 = rell[j + 1];
        int s2 = rell[j + 2];
        int s3 = rell[j + 3];
        float2 v0 = *(const float2*)&feat[(size_t)s0 * D + 2 * lane];
        float2 v1 = *(const float2*)&feat[(size_t)s1 * D + 2 * lane];
        float2 v2 = *(const float2*)&feat[(size_t)s2 * D + 2 * lane];
        float2 v3 = *(const float2*)&feat[(size_t)s3 * D + 2 * lane];
        acc.x += v0.x + v1.x + v2.x + v3.x;
        acc.y += v0.y + v1.y + v2.y + v3.y;
    }
    for (; j < n; ++j) {
        int s = rell[j];
        float2 v = *(const float2*)&feat[(size_t)s * D + 2 * lane];
        acc.x += v.x;
        acc.y += v.y;
    }
    unsigned lo16 = f2bf(acc.x * inv);
    unsigned hi16 = f2bf(acc.y * inv);
    hneigh_u32[(size_t)row * 64 + lane] = lo16 | (hi16 << 16);
}

// ---- bf16 MFMA GEMM: full[rowpos[m]] = feat[m] @ Wself^T + hneigh[m] @ Wneigh^T ----
// W staged once in LDS (XOR chunk-swizzle); K-loop has NO barriers: A frags come
// straight from global, B frags from static LDS.
__global__ __launch_bounds__(256, 2)
void gemm_kernel(const float* __restrict__ feat,
                 const unsigned short* __restrict__ hneigh,   // bf16 bits [N_DST][128]
                 const unsigned short* __restrict__ wbf,      // bf16 bits [128][256]
                 const int* __restrict__ rowpos,
                 float* __restrict__ full) {
    __shared__ unsigned short Wl[128 * 256];   // 64 KiB; chunk c of row n at c^(n&7)

    int tid = threadIdx.x;
    {   // stage W: 16-B chunks, swizzled
        int n = tid >> 1;
        int ckbase = (tid & 1) * 16;
        const uint4* s = (const uint4*)(wbf + n * 256);
        uint4* d = (uint4*)(Wl + n * 256);
#pragma unroll
        for (int i = 0; i < 16; ++i) {
            int ck = ckbase + i;
            d[ck ^ (n & 7)] = s[ck];
        }
    }
    __syncthreads();

    int wv   = tid >> 6;
    int lane = tid & 63;
    int l15  = lane & 15;
    int q    = lane >> 4;
    int rowbase = blockIdx.x * 128 + wv * 32;

    f32x4 acc[2][8];
#pragma unroll
    for (int rt = 0; rt < 2; ++rt)
#pragma unroll
        for (int ct = 0; ct < 8; ++ct) acc[rt][ct] = (f32x4){0.f, 0.f, 0.f, 0.f};

    int r0c = min(rowbase + l15,      N_DST - 1);
    int r1c = min(rowbase + 16 + l15, N_DST - 1);

    // Phase 1: k = 0..127 from feat (fp32 -> bf16 in regs)
#pragma unroll 1
    for (int s = 0; s < 4; ++s) {
        int k0 = s * 32 + q * 8;
        float4 a0lo = *(const float4*)(feat + (size_t)r0c * D + k0);
        float4 a0hi = *(const float4*)(feat + (size_t)r0c * D + k0 + 4);
        float4 a1lo = *(const float4*)(feat + (size_t)r1c * D + k0);
        float4 a1hi = *(const float4*)(feat + (size_t)r1c * D + k0 + 4);
        union { bf16x8 v; unsigned short u[8]; } a0, a1;
        a0.u[0] = f2bf(a0lo.x); a0.u[1] = f2bf(a0lo.y);
        a0.u[2] = f2bf(a0lo.z); a0.u[3] = f2bf(a0lo.w);
        a0.u[4] = f2bf(a0hi.x); a0.u[5] = f2bf(a0hi.y);
        a0.u[6] = f2bf(a0hi.z); a0.u[7] = f2bf(a0hi.w);
        a1.u[0] = f2bf(a1lo.x); a1.u[1] = f2bf(a1lo.y);
        a1.u[2] = f2bf(a1lo.z); a1.u[3] = f2bf(a1lo.w);
        a1.u[4] = f2bf(a1hi.x); a1.u[5] = f2bf(a1hi.y);
        a1.u[6] = f2bf(a1hi.z); a1.u[7] = f2bf(a1hi.w);
#pragma unroll
        for (int ct = 0; ct < 8; ++ct) {
            int n = ct * 16 + l15;
            int ck = s * 4 + q;
            bf16x8 b = *(const bf16x8*)(Wl + n * 256 + ((ck ^ (n & 7)) << 3));
            acc[0][ct] = __builtin_amdgcn_mfma_f32_16x16x32_bf16(a0.v, b, acc[0][ct], 0, 0, 0);
            acc[1][ct] = __builtin_amdgcn_mfma_f32_16x16x32_bf16(a1.v, b, acc[1][ct], 0, 0, 0);
        }
    }
    // Phase 2: k = 128..255 from hneigh (already bf16)
#pragma unroll 1
    for (int s = 0; s < 4; ++s) {
        int k0 = s * 32 + q * 8;
        bf16x8 a0 = *(const bf16x8*)(hneigh + (size_t)r0c * D + k0);
        bf16x8 a1 = *(const bf16x8*)(hneigh + (size_t)r1c * D + k0);
#pragma unroll
        for (int ct = 0; ct < 8; ++ct) {
            int n = ct * 16 + l15;
            int ck = 16 + s * 4 + q;
            bf16x8 b = *(const bf16x8*)(Wl + n * 256 + ((ck ^ (n & 7)) << 3));
            acc[0][ct] = __builtin_amdgcn_mfma_f32_16x16x32_bf16(a0, b, acc[0][ct], 0, 0, 0);
            acc[1][ct] = __builtin_amdgcn_mfma_f32_16x16x32_bf16(a1, b, acc[1][ct], 0, 0, 0);
        }
    }

    // epilogue: C/D layout col=l15, row=q*4+reg; scatter rows via rowpos
#pragma unroll
    for (int rt = 0; rt < 2; ++rt) {
#pragma unroll
        for (int reg = 0; reg < 4; ++reg) {
            int gm = rowbase + rt * 16 + q * 4 + reg;
            if (gm < N_DST) {
                int jj = rowpos[gm];
                float* outr = full + (size_t)jj * D + l15;
#pragma unroll
                for (int ct = 0; ct < 8; ++ct)
                    outr[ct * 16] = acc[rt][ct][reg];
            }
        }
    }
}

// ---------------- reuse rows: full[reuse_idx[r]] = emb[r] ----------------
__global__ void reuse_copy_kernel(const float* __restrict__ emb,
                                  const int* __restrict__ ridx,
                                  float* __restrict__ full, int n) {
    int idx = blockIdx.x * blockDim.x + threadIdx.x;
    int r = idx >> 5;
    if (r >= n) return;
    int c4 = (idx & 31) * 4;
    *(float4*)&full[ridx[r] * D + c4] = *(const float4*)&emb[r * D + c4];
}

// ---------------- cache gather: out[t] = full[cidx[t]] ----------------
__global__ void cache_gather_kernel(const float* __restrict__ full,
                                    const int* __restrict__ cidx,
                                    float* __restrict__ out, int n) {
    int idx = blockIdx.x * blockDim.x + threadIdx.x;
    int r = idx >> 5;
    if (r >= n) return;
    int c4 = (idx & 31) * 4;
    *(float4*)&out[r * D + c4] = *(const float4*)&full[cidx[r] * D + c4];
}

extern "C" void kernel_launch(void* const* d_in, const int* in_sizes, int n_in,
                              void* d_out, int out_size, void* d_ws, size_t ws_size,
                              hipStream_t stream) {
    const float* feat_src  = (const float*)d_in[0];
    const float* W_self    = (const float*)d_in[1];
    const float* W_neigh   = (const float*)d_in[2];
    const float* reuse_emb = (const float*)d_in[3];
    const int*   src       = (const int*)d_in[4];
    const int*   dst       = (const int*)d_in[5];
    const int*   reuse_idx = (const int*)d_in[6];
    const int*   cache_idx = (const int*)d_in[7];

    int n_edges = in_sizes[4];
    int n_reuse = in_sizes[6];
    int n_cache = in_sizes[7];
    int full_len = N_DST + n_reuse;

    // ws layout: hneigh bf16 (12.8 MB) | cnt (200 KB) | rowpos (200 KB) | wbf (64 KB)
    unsigned short* hneigh = (unsigned short*)d_ws;
    int*   cnt    = (int*)(hneigh + (size_t)N_DST * D);
    int*   rowpos = cnt + N_DST;
    unsigned short* wbf = (unsigned short*)(rowpos + N_DST);

    float* full = (float*)d_out;                      // 55000*128 fp32
    float* cache_out = full + (size_t)full_len * D;   // 8000*128

    // ELL adjacency (25.6 MB) borrows d_out's `full` region (28.2 MB): consumed
    // by gather_kernel before gemm overwrites it; every byte of d_out rewritten.
    int* ell = (int*)full;

    hipMemsetAsync(cnt, 0, (size_t)N_DST * sizeof(int), stream);

    build_ell_kernel<<<(n_edges + 255) / 256, 256, 0, stream>>>(
        src, dst, ell, cnt, n_edges);

    rowpos_kernel<<<(N_DST + 255) / 256, 256, 0, stream>>>(
        reuse_idx, rowpos, n_reuse);

    wconv_kernel<<<(128 * 256 + 255) / 256, 256, 0, stream>>>(
        W_self, W_neigh, wbf);

    gather_kernel<<<(N_DST * 64 + 255) / 256, 256, 0, stream>>>(
        feat_src, ell, cnt, (unsigned int*)hneigh);

    gemm_kernel<<<(N_DST + 127) / 128, 256, 0, stream>>>(
        feat_src, hneigh, wbf, rowpos, full);

    reuse_copy_kernel<<<(n_reuse * 32 + 255) / 256, 256, 0, stream>>>(
        reuse_emb, reuse_idx, full, n_reuse);

    cache_gather_kernel<<<(n_cache * 32 + 255) / 256, 256, 0, stream>>>(
        full, cache_idx, cache_out, n_cache);
}